// Round 13
// baseline (1176.118 us; speedup 1.0000x reference)
//
#include <hip/hip_runtime.h>

#define NROW 16384
#define DDIM 128
#define NITER (NROW / 64)

typedef _Float16 f16x8 __attribute__((ext_vector_type(8)));
typedef __fp16 fp16x2 __attribute__((ext_vector_type(2)));
typedef float f32x4 __attribute__((ext_vector_type(4)));

__device__ __forceinline__ unsigned short f2h(float x) {
  union { _Float16 f; unsigned short u; } cvt;
  cvt.f = (_Float16)x;  // RNE
  return cvt.u;
}

__device__ __forceinline__ unsigned pkrtz(float a, float b) {
  union { fp16x2 h; unsigned u; } cvt;
  cvt.h = __builtin_amdgcn_cvt_pkrtz(a, b);  // v_cvt_pkrtz_f16_f32
  return cvt.u;
}

// Raw barrier without the compiler's vmcnt(0) drain: lets prefetch loads
// stay in flight across the barrier (m97 barrier-drain workaround).
__device__ __forceinline__ void block_sync() {
  asm volatile("s_waitcnt lgkmcnt(0)" ::: "memory");  // ds ops drained
  __builtin_amdgcn_s_barrier();
  asm volatile("" ::: "memory");                      // no hoisting of reads
}

// ---------------- prep: ht[d][i] = fp16(h[i][d]) ----------------
__global__ __launch_bounds__(256) void prep_ht(const float* __restrict__ h,
                                               unsigned short* __restrict__ ht) {
  __shared__ unsigned short tile[DDIM][65];  // 65: 2-way-free transpose
  const int t = threadIdx.x;
  const int i0 = blockIdx.x * 64;
#pragma unroll
  for (int rep = 0; rep < 8; ++rep) {
    int idx = rep * 256 + t;          // 0..2047 float4s of a 64x128 tile
    int r = idx >> 5, c4 = idx & 31;
    const float4 v = *(const float4*)(h + (size_t)(i0 + r) * DDIM + c4 * 4);
    int c = c4 * 4;
    tile[c + 0][r] = f2h(v.x);
    tile[c + 1][r] = f2h(v.y);
    tile[c + 2][r] = f2h(v.z);
    tile[c + 3][r] = f2h(v.w);
  }
  __syncthreads();
#pragma unroll
  for (int rep = 0; rep < 4; ++rep) {
    int idx = rep * 256 + t;          // 0..1023 groups of 8
    int d = idx >> 3, io = (idx & 7) * 8;
    uint4 o;
    o.x = (unsigned)tile[d][io + 0] | ((unsigned)tile[d][io + 1] << 16);
    o.y = (unsigned)tile[d][io + 2] | ((unsigned)tile[d][io + 3] << 16);
    o.z = (unsigned)tile[d][io + 4] | ((unsigned)tile[d][io + 5] << 16);
    o.w = (unsigned)tile[d][io + 6] | ((unsigned)tile[d][io + 7] << 16);
    *(uint4*)(ht + (size_t)d * NROW + i0 + io) = o;
  }
}

// ---------------- fused: out = rownorm(exp(adj)) @ h ----------------
// R8 skeleton (proven best, 246.8us) with ONE variable changed: global
// prefetch burst length. Registers hold a GROUP of 4 k-tiles; the entire
// next group (A: 1KB/row, B: 512B/d-row contiguous) is fetched in one clump
// once per 4 iterations. Barrier cadence, LDS layout (40KB, 2 blocks/CU),
// swizzle maps, ones-column rowsum, epilogue: byte-identical to R8.
// j-loop fully unrolled so all pa/pb indices are compile-time (rule #20).
__global__ __launch_bounds__(256, 2) void fused(const float* __restrict__ adj,
                                                const unsigned short* __restrict__ ht,
                                                float* __restrict__ out) {
  __shared__ __align__(16) char smem[40960];  // A: 2*4KB @0, BT: 2*16KB @8192
  const int t = threadIdx.x;
  const size_t m0 = (size_t)blockIdx.x * 32;

  // --- staging indices (pre-swizzled source chunk) ---
  const int srow = t >> 3;                         // 0..31
  const int chk = (t & 7) ^ (srow & 7);            // semantic 8-elem chunk
  const float* ap = adj + (m0 + srow) * (size_t)NROW + chk * 8;
  const unsigned short* hp = ht + (size_t)srow * NROW + chk * 8;

  // --- mfma indices ---
  const int l = t & 63, w = t >> 6;
  const int wr = w >> 1, wc = w & 1;
  const int lr = l & 15, kg = l >> 4;              // kg: k-group 0..3
  const int arow = wr * 16 + lr;                   // 0..31
  const int aoff0 = arow * 128 + (((kg    ) ^ (arow & 7)) << 4);
  const int aoff1 = arow * 128 + (((kg + 4) ^ (arow & 7)) << 4);
  const int d0 = wc * 64 + lr;                     // d&7 == lr&7 for all cf
  const int boff0 = d0 * 128 + (((kg    ) ^ (lr & 7)) << 4);
  const int boff1 = d0 * 128 + (((kg + 4) ^ (lr & 7)) << 4);

  f32x4 acc[4];
#pragma unroll
  for (int cf = 0; cf < 4; ++cf) acc[cf] = (f32x4){0.f, 0.f, 0.f, 0.f};
  f32x4 rsum = (f32x4){0.f, 0.f, 0.f, 0.f};  // rowsum via ones-column MFMA

  f16x8 ones;
#pragma unroll
  for (int e = 0; e < 8; ++e) ones[e] = (_Float16)1.0f;

  // group-of-4 register prefetch buffers
  float4 pa[4][2];
  uint4 pb[4][4];

  // prologue: fetch group 0 (tiles 0..3) in one clump
#pragma unroll
  for (int jj = 0; jj < 4; ++jj) {
#pragma unroll
    for (int q = 0; q < 4; ++q)
      pb[jj][q] = *(const uint4*)(hp + jj * 64 + q * 32 * NROW);
    pa[jj][0] = *(const float4*)(ap + jj * 64);
    pa[jj][1] = *(const float4*)(ap + jj * 64 + 4);
  }

  for (int ig = 0; ig < NITER / 4; ++ig) {
#pragma unroll
    for (int j = 0; j < 4; ++j) {
      const int cur = j & 1;  // compile-time buffer index (ig*4 is even)

      // 1. B LDS writes first (independent of exp -> overlaps VALU chain)
      uint4* bb = (uint4*)(smem + 8192 + cur * 16384);
      bb[t] = pb[j][0]; bb[t + 256] = pb[j][1];
      bb[t + 512] = pb[j][2]; bb[t + 768] = pb[j][3];

      // 2. stash A regs (slot j fully free after this)
      const float4 a0 = pa[j][0], a1 = pa[j][1];

      // 2b. on the last sub-iter, fetch the ENTIRE next group in one clump:
      // A: 1KB contiguous per adj row; B: 512B contiguous per ht d-row.
      if (j == 3 && ig + 1 < NITER / 4) {
        const unsigned short* hb = hp + (ig + 1) * 256;
        const float* a = ap + (ig + 1) * 256;
#pragma unroll
        for (int jj = 0; jj < 4; ++jj) {
#pragma unroll
          for (int q = 0; q < 4; ++q)
            pb[jj][q] = *(const uint4*)(hb + jj * 64 + q * 32 * NROW);
          pa[jj][0] = *(const float4*)(a + jj * 64);
          pa[jj][1] = *(const float4*)(a + jj * 64 + 4);
        }
      }

      // 3. exp + pkrtz pack
      uint4 aw;
      aw.x = pkrtz(__expf(a0.x), __expf(a0.y));
      aw.y = pkrtz(__expf(a0.z), __expf(a0.w));
      aw.z = pkrtz(__expf(a1.x), __expf(a1.y));
      aw.w = pkrtz(__expf(a1.z), __expf(a1.w));

      // 4. A LDS write
      *(uint4*)(smem + cur * 4096 + t * 16) = aw;

      // 5. barrier (LDS visible; global prefetch stays in flight)
      block_sync();

      // 6. fragments + MFMA (rowsum folded in via ones-column)
      const char* aB = smem + cur * 4096;
      const char* bB = smem + 8192 + cur * 16384;
      __builtin_amdgcn_s_setprio(1);
      f16x8 af0 = *(const f16x8*)(aB + aoff0);
      f16x8 af1 = *(const f16x8*)(aB + aoff1);
      rsum = __builtin_amdgcn_mfma_f32_16x16x32_f16(af0, ones, rsum, 0, 0, 0);
#pragma unroll
      for (int cf = 0; cf < 4; ++cf) {
        f16x8 bf0 = *(const f16x8*)(bB + boff0 + cf * 2048);
        acc[cf] = __builtin_amdgcn_mfma_f32_16x16x32_f16(af0, bf0, acc[cf], 0, 0, 0);
      }
      rsum = __builtin_amdgcn_mfma_f32_16x16x32_f16(af1, ones, rsum, 0, 0, 0);
#pragma unroll
      for (int cf = 0; cf < 4; ++cf) {
        f16x8 bf1 = *(const f16x8*)(bB + boff1 + cf * 2048);
        acc[cf] = __builtin_amdgcn_mfma_f32_16x16x32_f16(af1, bf1, acc[cf], 0, 0, 0);
      }
      __builtin_amdgcn_s_setprio(0);
    }
  }

  // epilogue: D[(kg*4+r)][lr]; rsum[r] holds this lane's row's sum
#pragma unroll
  for (int r = 0; r < 4; ++r) {
    const int row_l = wr * 16 + kg * 4 + r;
    const float inv = 1.0f / rsum[r];
    float* orow = out + (m0 + row_l) * (size_t)DDIM + wc * 64 + lr;
#pragma unroll
    for (int cf = 0; cf < 4; ++cf) {
      orow[cf * 16] = acc[cf][r] * inv;
    }
  }
}

extern "C" void kernel_launch(void* const* d_in, const int* in_sizes, int n_in,
                              void* d_out, int out_size, void* d_ws, size_t ws_size,
                              hipStream_t stream) {
  (void)in_sizes; (void)n_in; (void)out_size; (void)ws_size;
  const float* h   = (const float*)d_in[0];
  const float* adj = (const float*)d_in[1];
  float* out = (float*)d_out;
  unsigned short* ht = (unsigned short*)d_ws;  // 128*16384 fp16 = 4 MB

  prep_ht<<<dim3(NROW / 64), dim3(256), 0, stream>>>(h, ht);
  fused<<<dim3(NROW / 32), dim3(256), 0, stream>>>(adj, ht, out);
}

// Round 14
// 279.041 us; speedup vs baseline: 4.2149x; 4.2149x over previous
//
#include <hip/hip_runtime.h>

#define NROW 16384
#define DDIM 128
#define NITER (NROW / 64)

typedef _Float16 f16x8 __attribute__((ext_vector_type(8)));
typedef __fp16 fp16x2 __attribute__((ext_vector_type(2)));
typedef float f32x4 __attribute__((ext_vector_type(4)));

__device__ __forceinline__ unsigned short f2h(float x) {
  union { _Float16 f; unsigned short u; } cvt;
  cvt.f = (_Float16)x;  // RNE
  return cvt.u;
}

__device__ __forceinline__ unsigned pkrtz(float a, float b) {
  union { fp16x2 h; unsigned u; } cvt;
  cvt.h = __builtin_amdgcn_cvt_pkrtz(a, b);  // v_cvt_pkrtz_f16_f32
  return cvt.u;
}

__device__ __forceinline__ void gll16(const void* g, void* l) {
  __builtin_amdgcn_global_load_lds(
      (const __attribute__((address_space(1))) unsigned int*)g,
      (__attribute__((address_space(3))) unsigned int*)l, 16, 0, 0);
}

// ---------------- prep: ht[d][i] = fp16(h[i][d]) ----------------
__global__ __launch_bounds__(256) void prep_ht(const float* __restrict__ h,
                                               unsigned short* __restrict__ ht) {
  __shared__ unsigned short tile[DDIM][65];  // 65: 2-way-free transpose
  const int t = threadIdx.x;
  const int i0 = blockIdx.x * 64;
#pragma unroll
  for (int rep = 0; rep < 8; ++rep) {
    int idx = rep * 256 + t;          // 0..2047 float4s of a 64x128 tile
    int r = idx >> 5, c4 = idx & 31;
    const float4 v = *(const float4*)(h + (size_t)(i0 + r) * DDIM + c4 * 4);
    int c = c4 * 4;
    tile[c + 0][r] = f2h(v.x);
    tile[c + 1][r] = f2h(v.y);
    tile[c + 2][r] = f2h(v.z);
    tile[c + 3][r] = f2h(v.w);
  }
  __syncthreads();
#pragma unroll
  for (int rep = 0; rep < 4; ++rep) {
    int idx = rep * 256 + t;          // 0..1023 groups of 8
    int d = idx >> 3, io = (idx & 7) * 8;
    uint4 o;
    o.x = (unsigned)tile[d][io + 0] | ((unsigned)tile[d][io + 1] << 16);
    o.y = (unsigned)tile[d][io + 2] | ((unsigned)tile[d][io + 3] << 16);
    o.z = (unsigned)tile[d][io + 4] | ((unsigned)tile[d][io + 5] << 16);
    o.w = (unsigned)tile[d][io + 6] | ((unsigned)tile[d][io + 7] << 16);
    *(uint4*)(ht + (size_t)d * NROW + i0 + io) = o;
  }
}

// ---------------- fused: out = rownorm(exp(adj)) @ h ----------------
// R8 skeleton (246.8us best) with B staging via global_load_lds DMA into a
// TRIPLE buffer (deep pipeline; fixes R11's 1-phase slack):
//   iter t: A) exp/pack A(t) -> 1 ds_write   B) A(t+1) global prefetch
//           C) lgkmcnt(0); s_waitcnt vmcnt(6); s_barrier
//           D) DMA B(t+2) -> bbuf[(t+2)%3]   (prior readers drained at C)
//           E) ds_read frags bbuf[t%3]; MFMA (+ones rowsum)
// vmcnt(6) leaves the 6 newest (B(t+2) 4 + A(t+1) 2) in flight and drains
// B(t+1), which was issued ~2 iterations (~4000 cyc) earlier. In-order
// retirement: step A's implicit wait on A(t) leaves newer B DMAs in flight.
// LDS: A 2x4KB @0, B 3x16KB @8192 = 56KB -> 2 blocks/CU.
__global__ __launch_bounds__(256, 2) void fused(const float* __restrict__ adj,
                                                const unsigned short* __restrict__ ht,
                                                float* __restrict__ out) {
  __shared__ __align__(16) char smem[57344];
  const int t = threadIdx.x;
  const size_t m0 = (size_t)blockIdx.x * 32;

  // --- staging indices (pre-swizzled source chunk) ---
  const int srow = t >> 3;                         // 0..31
  const int chk = (t & 7) ^ (srow & 7);            // semantic 8-elem chunk
  const float* ap = adj + (m0 + srow) * (size_t)NROW + chk * 8;
  const unsigned short* hp = ht + (size_t)srow * NROW + chk * 8;

  // --- mfma indices ---
  const int l = t & 63, w = t >> 6;
  const int wr = w >> 1, wc = w & 1;
  const int lr = l & 15, kg = l >> 4;              // kg: k-group 0..3
  const int arow = wr * 16 + lr;                   // 0..31
  const int aoff0 = arow * 128 + (((kg    ) ^ (arow & 7)) << 4);
  const int aoff1 = arow * 128 + (((kg + 4) ^ (arow & 7)) << 4);
  const int d0 = wc * 64 + lr;                     // d&7 == lr&7 for all cf
  const int boff0 = d0 * 128 + (((kg    ) ^ (lr & 7)) << 4);
  const int boff1 = d0 * 128 + (((kg + 4) ^ (lr & 7)) << 4);

  // DMA dest: wave-uniform base + HW lane*16 -> byte j*4096 + t*16,
  // byte-identical to R8's staged layout (verified R11).
  const int dmaw = w * 1024;

  f32x4 acc[4];
#pragma unroll
  for (int cf = 0; cf < 4; ++cf) acc[cf] = (f32x4){0.f, 0.f, 0.f, 0.f};
  f32x4 rsum = (f32x4){0.f, 0.f, 0.f, 0.f};  // rowsum via ones-column MFMA

  f16x8 ones;
#pragma unroll
  for (int e = 0; e < 8; ++e) ones[e] = (_Float16)1.0f;

  // ---- prologue: DMA tiles 0,1 into bufs 0,1; A(0) regs ----
#pragma unroll
  for (int j = 0; j < 4; ++j)
    gll16(hp + j * 32 * NROW, smem + 8192 + j * 4096 + dmaw);
#pragma unroll
  for (int j = 0; j < 4; ++j)
    gll16(hp + 64 + j * 32 * NROW, smem + 8192 + 16384 + j * 4096 + dmaw);
  float4 pa0 = *(const float4*)(ap);
  float4 pa1 = *(const float4*)(ap + 4);

  int br = 0;        // buffer holding tile 'it'
  int bw = 2;        // buffer for tile 'it+2' = (br+2)%3

  for (int it = 0; it < NITER; ++it) {
    const int cur = it & 1;

    // A. exp + pkrtz pack + single A ds_write (waits A(it); B DMAs newer)
    const float4 a0 = pa0, a1 = pa1;
    uint4 aw;
    aw.x = pkrtz(__expf(a0.x), __expf(a0.y));
    aw.y = pkrtz(__expf(a0.z), __expf(a0.w));
    aw.z = pkrtz(__expf(a1.x), __expf(a1.y));
    aw.w = pkrtz(__expf(a1.z), __expf(a1.w));
    *(uint4*)(smem + cur * 4096 + t * 16) = aw;

    // B. A global prefetch for it+1 (wraps harmlessly on last iter)
    {
      const float* a = ap + ((it + 1) & 255) * 64;
      pa0 = *(const float4*)(a);
      pa1 = *(const float4*)(a + 4);
    }

    // C. rendezvous: A write drained; counted vmcnt keeps 6 newest in flight
    asm volatile("s_waitcnt lgkmcnt(0)" ::: "memory");
    asm volatile("s_waitcnt vmcnt(6)" ::: "memory");
    __builtin_amdgcn_s_barrier();
    asm volatile("" ::: "memory");

    // D. DMA B(it+2) -> bbuf[bw] (prior readers of bw drained at C's barrier;
    //    wraps to tiles 0/1 at the end, into buffers never read again)
    {
      const unsigned short* hb = hp + ((it + 2) & 255) * 64;
      char* dst = smem + 8192 + bw * 16384 + dmaw;
#pragma unroll
      for (int j = 0; j < 4; ++j)
        gll16(hb + j * 32 * NROW, dst + j * 4096);
    }

    // E. fragments + MFMA (rowsum folded in via ones-column)
    const char* aB = smem + cur * 4096;
    const char* bB = smem + 8192 + br * 16384;
    __builtin_amdgcn_s_setprio(1);
    f16x8 af0 = *(const f16x8*)(aB + aoff0);
    f16x8 af1 = *(const f16x8*)(aB + aoff1);
    rsum = __builtin_amdgcn_mfma_f32_16x16x32_f16(af0, ones, rsum, 0, 0, 0);
#pragma unroll
    for (int cf = 0; cf < 4; ++cf) {
      f16x8 bf0 = *(const f16x8*)(bB + boff0 + cf * 2048);
      acc[cf] = __builtin_amdgcn_mfma_f32_16x16x32_f16(af0, bf0, acc[cf], 0, 0, 0);
    }
    rsum = __builtin_amdgcn_mfma_f32_16x16x32_f16(af1, ones, rsum, 0, 0, 0);
#pragma unroll
    for (int cf = 0; cf < 4; ++cf) {
      f16x8 bf1 = *(const f16x8*)(bB + boff1 + cf * 2048);
      acc[cf] = __builtin_amdgcn_mfma_f32_16x16x32_f16(af1, bf1, acc[cf], 0, 0, 0);
    }
    __builtin_amdgcn_s_setprio(0);

    // rotate buffers
    br = (br == 2) ? 0 : br + 1;
    bw = (bw == 2) ? 0 : bw + 1;
  }

  // epilogue: D[(kg*4+r)][lr]; rsum[r] holds this lane's row's sum
#pragma unroll
  for (int r = 0; r < 4; ++r) {
    const int row_l = wr * 16 + kg * 4 + r;
    const float inv = 1.0f / rsum[r];
    float* orow = out + (m0 + row_l) * (size_t)DDIM + wc * 64 + lr;
#pragma unroll
    for (int cf = 0; cf < 4; ++cf) {
      orow[cf * 16] = acc[cf][r] * inv;
    }
  }
}

extern "C" void kernel_launch(void* const* d_in, const int* in_sizes, int n_in,
                              void* d_out, int out_size, void* d_ws, size_t ws_size,
                              hipStream_t stream) {
  (void)in_sizes; (void)n_in; (void)out_size; (void)ws_size;
  const float* h   = (const float*)d_in[0];
  const float* adj = (const float*)d_in[1];
  float* out = (float*)d_out;
  unsigned short* ht = (unsigned short*)d_ws;  // 128*16384 fp16 = 4 MB

  prep_ht<<<dim3(NROW / 64), dim3(256), 0, stream>>>(h, ht);
  fused<<<dim3(NROW / 32), dim3(256), 0, stream>>>(adj, ht, out);
}